// Round 3
// baseline (759.346 us; speedup 1.0000x reference)
//
#include <hip/hip_runtime.h>
#include <stdint.h>

// LSTMNet: B=2048, T=512, IN=64, H=64, 4H=256, 2 layers, FC to 4 classes.
// R6b: identical to R6 (previous round was an infra failure, not a kernel
// verdict — re-audited: alignment, dataflow, bounds, numerics all check).
// Full-M MFMA packing via fp16 (no hi/lo split).
//  - A and W in fp16 (2^-11 rel err) replaces {A bf16 hi/lo, W bf16-hi (2^-8)}
//    => error should IMPROVE vs R5's 9.8e-4, and all lo-split machinery dies.
//  - NB=8 batches/WG, batch b at panel row 4*(b>>1)+(b&1): lane kg owns
//    batches 2kg (acc[g][0]) and 2kg+1 (acc[g][1]) - no cross-lane fold.
//  - 256 WGs x 512 thr = 1 block/CU, 8 waves (4 L0 + 4 L1, L1 lags 1 step).
//  - Per-CU per-iter: MFMA 256->128, ds_read_b128 64->32, LDS writes halved.
//  - Ping-pong panels, ONE barrier/iter (unchanged from R5).
//  - x staged by L1 waves: 2 cols/lane via float2 load, packed b32 LDS write.

#define T_SEQ 512
#define NB    8
#define PSTR  136          // A-panel row stride (fp16): 272B, 16B-aligned b128
#define PANEL (16 * PSTR)

typedef __attribute__((ext_vector_type(8))) _Float16 half8;  // 8 x f16 (4 VGPR)
typedef __attribute__((ext_vector_type(4))) float    float4v; // MFMA C/D

__device__ __forceinline__ float sigm(float x) {
    return __builtin_amdgcn_rcpf(1.0f + __builtin_amdgcn_exp2f(-1.44269504088896f * x));
}
__device__ __forceinline__ float tanh_f(float x) {
    float e = __builtin_amdgcn_exp2f(-2.88539008177793f * x);   // exp(-2x)
    return __builtin_fmaf(2.0f, __builtin_amdgcn_rcpf(1.0f + e), -1.0f);
}

__global__ __launch_bounds__(512, 2) void lstm2_kernel(
    const float* __restrict__ x,
    const float* __restrict__ wih0, const float* __restrict__ whh0,
    const float* __restrict__ bih0, const float* __restrict__ bhh0,
    const float* __restrict__ wih1, const float* __restrict__ whh1,
    const float* __restrict__ bih1, const float* __restrict__ bhh1,
    const float* __restrict__ fcw,  const float* __restrict__ fcb,
    float* __restrict__ out)
{
    // panel0: cols [0,64)=x_t, [64,128)=h_l0.  panel1: cols [64,128)=h_l1
    // (L1 reads h_l0 from panel0 cols 64+; dual-base trick as R5).
    // Rows: batch b at 4*(b>>1)+(b&1) -> rows {0,1,4,5,8,9,12,13}; rows
    // 4q+2,4q+3 stay zero (their C rows land in ignored acc regs 2,3).
    __shared__ __align__(16) unsigned short panel0[2][PANEL];
    __shared__ __align__(16) unsigned short panel1[2][PANEL];
    __shared__ float h2buf[NB * 64];
    __shared__ float fcw_s[256];
    __shared__ float fcb_s[4];

    const int tid  = threadIdx.x;
    const int lane = tid & 63;
    const int wave = tid >> 6;
    const int mrow = lane & 15;         // A m-row base / B n-within-tile / C col
    const int kg   = lane >> 4;         // k-quad / C row-group
    const int lset = wave >> 2;         // 0 = layer-0 waves, 1 = layer-1 waves
    const int ws   = wave & 3;          // h-slice [16*ws, 16*ws+16)
    const int b0   = blockIdx.x * NB;

    for (int i = tid; i < 256; i += 512) fcw_s[i] = fcw[i];
    if (tid < 4) fcb_s[tid] = fcb[tid];
    for (int i = tid; i < 2 * PANEL; i += 512) {
        panel0[0][i] = 0; panel1[0][i] = 0;   // flattened across both buffers
    }

    const float* wih  = lset ? wih1 : wih0;
    const float* whh  = lset ? whh1 : whh0;
    const float* bihp = lset ? bih1 : bih0;
    const float* bhhp = lset ? bhh1 : bhh0;

    // Per-lane gate biases: gate g at n = g*64 + ws*16 + mrow.
    float biasg[4];
    #pragma unroll
    for (int g = 0; g < 4; ++g) {
        const int idx = g * 64 + ws * 16 + mrow;
        biasg[g] = bihp[idx] + bhhp[idx];
    }

    // Weight B-frags (fp16): wave owns n-tiles {ws,4+ws,8+ws,12+ws} = gates
    // i,f,g,o of its slice. n = tile*16 + mrow, k = kt*32 + kg*8 + j.
    // Combined K=128: k<64 -> w_ih[n][k]; k>=64 -> w_hh[n][k-64].
    half8 whiF[4][4];
    #pragma unroll
    for (int g = 0; g < 4; ++g) {
        const int n = (g * 4 + ws) * 16 + mrow;
        #pragma unroll
        for (int kt = 0; kt < 4; ++kt) {
            const int k0 = kt * 32 + kg * 8;
            const float* src = (k0 < 64) ? (wih + n * 64 + k0)
                                         : (whh + n * 64 + (k0 - 64));
            half8 hv8;
            #pragma unroll
            for (int j = 0; j < 8; ++j) hv8[j] = (_Float16)src[j];
            whiF[g][kt] = hv8;
        }
    }

    __syncthreads();                    // panels zeroed
    if (tid < 256) {                    // stage x(0) into panel0[0]
        const int bx = tid >> 5, c0 = (tid & 31) * 2;
        const int row = 4 * (bx >> 1) + (bx & 1);
        const float* xs = x + ((size_t)(b0 + bx) * T_SEQ + 0) * 64 + c0;
        union { _Float16 h[2]; unsigned int u; } p2;
        p2.h[0] = (_Float16)xs[0];
        p2.h[1] = (_Float16)xs[1];
        *(unsigned int*)&panel0[0][row * PSTR + c0] = p2.u;
    }
    __syncthreads();

    // Per-lane constant addressing (shorts).
    const int fragoff = mrow * PSTR + kg * 8;
    const unsigned short* rdA = &panel0[0][0] + (lset ? 64 : 0) + fragoff; // kt 0,1
    const unsigned short* rdB = (lset ? &panel1[0][0] : &panel0[0][0]) + fragoff; // kt 2,3
    unsigned short* hP = lset ? &panel1[0][0] : &panel0[0][0];  // h-write panel
    const int hcol  = ws * 16 + mrow;
    const int hoffA = (4 * kg) * PSTR + 64 + hcol;   // batch 2kg   (acc reg 0)
    const int hoffB = hoffA + PSTR;                  // batch 2kg+1 (acc reg 1)
    // x staging (L1 waves): 256 lanes cover 8 batches x 64 cols, 2 cols/lane.
    const int st   = ((wave & 3) << 6) + lane;       // 0..255 within L1 set
    const int sbx  = st >> 5;                        // staging batch 0..7
    const int sc0  = (st & 31) * 2;                  // col pair
    const int sxof = (4 * (sbx >> 1) + (sbx & 1)) * PSTR + sc0;
    const float* xp = x + ((size_t)(b0 + sbx) * T_SEQ + 1) * 64 + sc0;  // t=1
    float cA = 0.f, cB = 0.f;
    const float4v z4 = {0.f, 0.f, 0.f, 0.f};

    for (int s = 0; s <= T_SEQ; ++s) {
        const int p    = s & 1;
        const int poff = p * PANEL;
        const int qoff = poff ^ PANEL;

        // Prefetch x(s+1) (L1 waves; wave-uniform condition).
        const bool do_stage = (lset == 1) && (s + 1 < T_SEQ);
        float xv0 = 0.f, xv1 = 0.f;
        if (do_stage) { xv0 = xp[0]; xv1 = xp[1]; }

        // ---- MFMA: 4 gate chains, depth 4 ----
        half8 af[4];
        {
            const unsigned short* bA = rdA + poff;
            const unsigned short* bB = rdB + poff;
            af[0] = *(const half8*)(bA);
            af[1] = *(const half8*)(bA + 32);
            af[2] = *(const half8*)(bB + 64);
            af[3] = *(const half8*)(bB + 96);
        }
        float4v acc[4];
        #pragma unroll
        for (int g = 0; g < 4; ++g)
            acc[g] = __builtin_amdgcn_mfma_f32_16x16x32_f16(af[0], whiF[g][0], z4, 0, 0, 0);
        #pragma unroll
        for (int kt = 1; kt < 4; ++kt) {
            #pragma unroll
            for (int g = 0; g < 4; ++g)
                acc[g] = __builtin_amdgcn_mfma_f32_16x16x32_f16(af[kt], whiF[g][kt], acc[g], 0, 0, 0);
        }

        // ---- Cell phase (writes go to the OTHER buffer; 1 barrier/iter) ----
        const bool active = lset ? (s > 0) : (s < T_SEQ);
        if (active) {                   // wave-uniform
            unsigned short* w = hP + qoff;
            // Cell A: batch 2kg (C row 4kg = reg 0)
            {
                float g0 = acc[0][0] + biasg[0];
                float g1 = acc[1][0] + biasg[1];
                float g2 = acc[2][0] + biasg[2];
                float g3 = acc[3][0] + biasg[3];
                float ig = sigm(g0), fg = sigm(g1);
                float gt = tanh_f(g2), og = sigm(g3);
                cA = fg * cA + ig * gt;
                float hv = og * tanh_f(cA);
                w[hoffA] = __builtin_bit_cast(unsigned short, (_Float16)hv);
                if (lset && s == T_SEQ) h2buf[(2 * kg) * 64 + hcol] = hv;
            }
            // Cell B: batch 2kg+1 (C row 4kg+1 = reg 1)
            {
                float g0 = acc[0][1] + biasg[0];
                float g1 = acc[1][1] + biasg[1];
                float g2 = acc[2][1] + biasg[2];
                float g3 = acc[3][1] + biasg[3];
                float ig = sigm(g0), fg = sigm(g1);
                float gt = tanh_f(g2), og = sigm(g3);
                cB = fg * cB + ig * gt;
                float hv = og * tanh_f(cB);
                w[hoffB] = __builtin_bit_cast(unsigned short, (_Float16)hv);
                if (lset && s == T_SEQ) h2buf[(2 * kg + 1) * 64 + hcol] = hv;
            }
        }
        if (do_stage) {                 // stage x(s+1) (L1 waves), packed b32
            union { _Float16 h[2]; unsigned int u; } p2;
            p2.h[0] = (_Float16)xv0;
            p2.h[1] = (_Float16)xv1;
            *(unsigned int*)(&panel0[0][0] + qoff + sxof) = p2.u;
            xp += 64;
        }
        __syncthreads();
    }

    // ---- FC head ----
    if (tid < 32) {
        const int bb = tid >> 2, nc = tid & 3;
        float s = fcb_s[nc];
        #pragma unroll 8
        for (int h = 0; h < 64; ++h) s += h2buf[bb * 64 + h] * fcw_s[nc * 64 + h];
        out[(size_t)(b0 + bb) * 4 + nc] = s;
    }
}

extern "C" void kernel_launch(void* const* d_in, const int* in_sizes, int n_in,
                              void* d_out, int out_size, void* d_ws, size_t ws_size,
                              hipStream_t stream) {
    const float* x    = (const float*)d_in[0];
    const float* wih0 = (const float*)d_in[1];
    const float* whh0 = (const float*)d_in[2];
    const float* bih0 = (const float*)d_in[3];
    const float* bhh0 = (const float*)d_in[4];
    const float* wih1 = (const float*)d_in[5];
    const float* whh1 = (const float*)d_in[6];
    const float* bih1 = (const float*)d_in[7];
    const float* bhh1 = (const float*)d_in[8];
    const float* fcw  = (const float*)d_in[9];
    const float* fcb  = (const float*)d_in[10];
    float* out = (float*)d_out;
    (void)d_ws; (void)ws_size; (void)in_sizes; (void)n_in; (void)out_size;

    lstm2_kernel<<<dim3(2048 / NB), dim3(512), 0, stream>>>(
        x, wih0, whh0, bih0, bhh0, wih1, whh1, bih1, bhh1, fcw, fcb, out);
}

// Round 4
// 694.742 us; speedup vs baseline: 1.0930x; 1.0930x over previous
//
#include <hip/hip_runtime.h>
#include <stdint.h>

// LSTMNet: B=2048, T=512, IN=64, H=64, 4H=256, 2 layers, FC to 4 classes.
// R7: latency/convoy attack. R6 proved the kernel is NOT issue-bound
// (halving instructions left iter latency ~flat at ~1us): it is pinned by
// the serialized chain around a single-block barrier domain.
//  - 512 WGs x 256 thr (NB=4) => 2 INDEPENDENT blocks/CU whose barriers
//    drift out of phase and fill each other's stalls (R5 evidence).
//  - Each wave handles its h-slice for BOTH layers (L0 step s, L1 step s-1,
//    lag-1, one barrier/iter): two independent MFMA chains + two cell
//    chains per wave = intra-wave ILP across the latency gaps.
//  - Shared A-frag: L0 kt{2,3} (h0) == L1 kt{0,1} => 6 ds_read_b128 not 8.
//  - Lane kg owns batch kg for both layers (rows 4kg): no exec masking.
//  - x prefetched 2 steps ahead in regs (body will shrink under HBM lat).
//  - panel1 shrunk to 64-col rows (PSTR2=72: 144B, 16B-aligned, 2-way-free).
//  - fp16 weights/activations as R6 (absmax 4.9e-4, threshold 3.16e-3).

#define T_SEQ  512
#define NB     4
#define PSTR   136          // panel0 row stride (shorts): 272B
#define PANEL  (16 * PSTR)
#define PSTR2  72           // panel1 row stride (shorts): 144B
#define PANEL2 (16 * PSTR2)

typedef __attribute__((ext_vector_type(8))) _Float16 half8;   // 8 x f16
typedef __attribute__((ext_vector_type(4))) float    float4v; // MFMA C/D

__device__ __forceinline__ float sigm(float x) {
    return __builtin_amdgcn_rcpf(1.0f + __builtin_amdgcn_exp2f(-1.44269504088896f * x));
}
__device__ __forceinline__ float tanh_f(float x) {
    float e = __builtin_amdgcn_exp2f(-2.88539008177793f * x);   // exp(-2x)
    return __builtin_fmaf(2.0f, __builtin_amdgcn_rcpf(1.0f + e), -1.0f);
}

__global__ __launch_bounds__(256, 2) void lstm2_kernel(
    const float* __restrict__ x,
    const float* __restrict__ wih0, const float* __restrict__ whh0,
    const float* __restrict__ bih0, const float* __restrict__ bhh0,
    const float* __restrict__ wih1, const float* __restrict__ whh1,
    const float* __restrict__ bih1, const float* __restrict__ bhh1,
    const float* __restrict__ fcw,  const float* __restrict__ fcb,
    float* __restrict__ out)
{
    // panel0: cols [0,64)=x_t, [64,128)=h_l0.  panel1: cols [0,64)=h_l1.
    // Rows: batch b at row 4b; other rows stay zero (their C rows land in
    // acc regs 1..3 which are ignored).
    __shared__ __align__(16) unsigned short panel0[2][PANEL];
    __shared__ __align__(16) unsigned short panel1[2][PANEL2];
    __shared__ float h2buf[NB * 64];
    __shared__ float fcw_s[256];
    __shared__ float fcb_s[4];

    const int tid  = threadIdx.x;
    const int lane = tid & 63;
    const int wave = tid >> 6;          // 0..3 = h-slice
    const int mrow = lane & 15;         // A m-row base / B n-within-tile / C col
    const int kg   = lane >> 4;         // k-quad / C row-group / lane's batch
    const int b0   = blockIdx.x * NB;

    fcw_s[tid & 255] = fcw[tid & 255];  // 256 threads, one each
    if (tid < 4) fcb_s[tid] = fcb[tid];
    for (int i = tid; i < 2 * PANEL; i += 256)  panel0[0][i] = 0;
    for (int i = tid; i < 2 * PANEL2; i += 256) panel1[0][i] = 0;

    const int hcol = wave * 16 + mrow;

    // Per-lane gate biases, both layers: gate g at n = g*64 + hcol.
    float bias0[4], bias1[4];
    #pragma unroll
    for (int g = 0; g < 4; ++g) {
        const int idx = g * 64 + hcol;
        bias0[g] = bih0[idx] + bhh0[idx];
        bias1[g] = bih1[idx] + bhh1[idx];
    }

    // Weight B-frags (fp16), both layers: wave owns n-tiles {w,4+w,8+w,12+w}
    // = gates i,f,g,o of its slice. n = tile*16 + mrow, k = kt*32 + kg*8 + j.
    // Combined K=128: k<64 -> w_ih[n][k]; k>=64 -> w_hh[n][k-64].
    half8 wf[2][4][4];                  // 128 VGPRs
    #pragma unroll
    for (int l = 0; l < 2; ++l) {
        const float* wihp = l ? wih1 : wih0;
        const float* whhp = l ? whh1 : whh0;
        #pragma unroll
        for (int g = 0; g < 4; ++g) {
            const int n = (g * 4 + wave) * 16 + mrow;
            #pragma unroll
            for (int kt = 0; kt < 4; ++kt) {
                const int k0 = kt * 32 + kg * 8;
                const float* src = (k0 < 64) ? (wihp + n * 64 + k0)
                                             : (whhp + n * 64 + (k0 - 64));
                half8 hv8;
                #pragma unroll
                for (int j = 0; j < 8; ++j) hv8[j] = (_Float16)src[j];
                wf[l][g][kt] = hv8;
            }
        }
    }

    __syncthreads();                    // panels zeroed
    // Stage x(0): wave w stages batch w, col = lane, row 4w.
    const int sxof = 4 * wave * PSTR + lane;
    {
        float xv = x[((size_t)(b0 + wave) * T_SEQ + 0) * 64 + lane];
        panel0[0][sxof] = __builtin_bit_cast(unsigned short, (_Float16)xv);
    }
    __syncthreads();

    // Per-lane constant addressing (shorts).
    const int fragoff  = mrow * PSTR  + kg * 8;
    const int fragoff2 = mrow * PSTR2 + kg * 8;
    const int h0off = 4 * kg * PSTR  + 64 + hcol;   // h0 write (panel0)
    const int h1off = 4 * kg * PSTR2 + hcol;        // h1 write (panel1)

    // x stream, 2 steps ahead: xcur holds x(s+1) at iter s.
    float xcur = x[((size_t)(b0 + wave) * T_SEQ + 1) * 64 + lane];
    const float* xp = x + ((size_t)(b0 + wave) * T_SEQ + 2) * 64 + lane;

    float c0 = 0.f, c1 = 0.f;
    const float4v z4 = {0.f, 0.f, 0.f, 0.f};

    for (int s = 0; s <= T_SEQ; ++s) {
        const int p     = s & 1;
        const int poff  = p * PANEL;
        const int poff2 = p * PANEL2;
        const int qoff  = poff  ^ PANEL;
        const int qoff2 = poff2 ^ PANEL2;

        // Issue x(s+2) load (wave-uniform condition).
        const bool ld = (s + 2) < T_SEQ;
        float xnext = 0.f;
        if (ld) xnext = *xp;

        // ---- A-frags: 6 unique b128 reads (L0 kt{2,3} == L1 kt{0,1}) ----
        const unsigned short* P0 = &panel0[0][0] + poff  + fragoff;
        const unsigned short* P1 = &panel1[0][0] + poff2 + fragoff2;
        half8 af0 = *(const half8*)(P0);        // x   k 0..31
        half8 af1 = *(const half8*)(P0 + 32);   // x   k32..63
        half8 af2 = *(const half8*)(P0 + 64);   // h0  k 0..31
        half8 af3 = *(const half8*)(P0 + 96);   // h0  k32..63
        half8 ag2 = *(const half8*)(P1);        // h1  k 0..31
        half8 ag3 = *(const half8*)(P1 + 32);   // h1  k32..63

        // ---- MFMA: 2 layers x 4 gate chains, depth 4 ----
        float4v a0[4], a1[4];
        #pragma unroll
        for (int g = 0; g < 4; ++g) {
            a0[g] = __builtin_amdgcn_mfma_f32_16x16x32_f16(af0, wf[0][g][0], z4, 0, 0, 0);
            a1[g] = __builtin_amdgcn_mfma_f32_16x16x32_f16(af2, wf[1][g][0], z4, 0, 0, 0);
        }
        #pragma unroll
        for (int g = 0; g < 4; ++g) {
            a0[g] = __builtin_amdgcn_mfma_f32_16x16x32_f16(af1, wf[0][g][1], a0[g], 0, 0, 0);
            a1[g] = __builtin_amdgcn_mfma_f32_16x16x32_f16(af3, wf[1][g][1], a1[g], 0, 0, 0);
        }
        #pragma unroll
        for (int g = 0; g < 4; ++g) {
            a0[g] = __builtin_amdgcn_mfma_f32_16x16x32_f16(af2, wf[0][g][2], a0[g], 0, 0, 0);
            a1[g] = __builtin_amdgcn_mfma_f32_16x16x32_f16(ag2, wf[1][g][2], a1[g], 0, 0, 0);
        }
        #pragma unroll
        for (int g = 0; g < 4; ++g) {
            a0[g] = __builtin_amdgcn_mfma_f32_16x16x32_f16(af3, wf[0][g][3], a0[g], 0, 0, 0);
            a1[g] = __builtin_amdgcn_mfma_f32_16x16x32_f16(ag3, wf[1][g][3], a1[g], 0, 0, 0);
        }

        // ---- Cells (writes go to the OTHER buffer; 1 barrier/iter) ----
        if (s < T_SEQ) {                // L0 cell for batch kg (wave-uniform)
            float g0 = a0[0][0] + bias0[0];
            float g1 = a0[1][0] + bias0[1];
            float g2 = a0[2][0] + bias0[2];
            float g3 = a0[3][0] + bias0[3];
            float ig = sigm(g0), fg = sigm(g1);
            float gt = tanh_f(g2), og = sigm(g3);
            c0 = fg * c0 + ig * gt;
            float hv = og * tanh_f(c0);
            panel0[0][qoff + h0off] = __builtin_bit_cast(unsigned short, (_Float16)hv);
        }
        if (s > 0) {                    // L1 cell for batch kg (wave-uniform)
            float g0 = a1[0][0] + bias1[0];
            float g1 = a1[1][0] + bias1[1];
            float g2 = a1[2][0] + bias1[2];
            float g3 = a1[3][0] + bias1[3];
            float ig = sigm(g0), fg = sigm(g1);
            float gt = tanh_f(g2), og = sigm(g3);
            c1 = fg * c1 + ig * gt;
            float hv = og * tanh_f(c1);
            panel1[0][qoff2 + h1off] = __builtin_bit_cast(unsigned short, (_Float16)hv);
            if (s == T_SEQ) h2buf[(kg << 6) + hcol] = hv;
        }
        if (s + 1 < T_SEQ) {            // stage x(s+1) from reg
            panel0[0][qoff + sxof] = __builtin_bit_cast(unsigned short, (_Float16)xcur);
        }
        xcur = xnext;
        if (ld) xp += 64;
        __syncthreads();
    }

    // ---- FC head ----
    if (tid < 16) {
        const int bb = tid >> 2, nc = tid & 3;
        float s = fcb_s[nc];
        #pragma unroll 8
        for (int h = 0; h < 64; ++h) s += h2buf[bb * 64 + h] * fcw_s[nc * 64 + h];
        out[(size_t)(b0 + bb) * 4 + nc] = s;
    }
}

extern "C" void kernel_launch(void* const* d_in, const int* in_sizes, int n_in,
                              void* d_out, int out_size, void* d_ws, size_t ws_size,
                              hipStream_t stream) {
    const float* x    = (const float*)d_in[0];
    const float* wih0 = (const float*)d_in[1];
    const float* whh0 = (const float*)d_in[2];
    const float* bih0 = (const float*)d_in[3];
    const float* bhh0 = (const float*)d_in[4];
    const float* wih1 = (const float*)d_in[5];
    const float* whh1 = (const float*)d_in[6];
    const float* bih1 = (const float*)d_in[7];
    const float* bhh1 = (const float*)d_in[8];
    const float* fcw  = (const float*)d_in[9];
    const float* fcb  = (const float*)d_in[10];
    float* out = (float*)d_out;
    (void)d_ws; (void)ws_size; (void)in_sizes; (void)n_in; (void)out_size;

    lstm2_kernel<<<dim3(2048 / NB), dim3(256), 0, stream>>>(
        x, wih0, whh0, bih0, bhh0, wih1, whh1, bih1, bhh1, fcw, fcb, out);
}